// Round 6
// baseline (101.740 us; speedup 1.0000x reference)
//
#include <hip/hip_runtime.h>

#define CINC 64
#define COUT 64
#define HH 32
#define WW 32
#define BB 16
#define NSPLIT 4
#define CPS 16            // cin per split

typedef __attribute__((ext_vector_type(8))) short short8;
typedef __attribute__((ext_vector_type(4))) float floatx4;

__device__ __forceinline__ unsigned short f2bf(float f) {
    union { float f; unsigned int u; } c; c.f = f;
    unsigned int r = (c.u + 0x7FFFu + ((c.u >> 16) & 1u)) >> 16;
    return (unsigned short)r;
}

// W3 layout: [split(4)][tap(9)][s(4)][oc(64)][q(4)][e(8)] bf16
// k = s*32 + q*8 + e (0..127), cin = split*16 + k/8, g = k%8
__global__ __launch_bounds__(256) void wt_kernel(const float* __restrict__ sw,
                                                 const float* __restrict__ sc,
                                                 short* __restrict__ W3) {
    __shared__ short lds[144 * 32];
    __shared__ float scl[CINC];
    const int oc = blockIdx.x;
    const int t = threadIdx.x;
    if (t < CINC) scl[t] = sc[oc * CINC + t];
    __syncthreads();
    for (int j = t; j < 4608; j += 256) {           // sw row: [cin][g][kh*3+kw]
        float w = sw[oc * 4608 + j];
        int cin = j / 72;
        int rem = j - cin * 72;
        int g = rem / 9;
        int tap = rem - g * 9;
        w *= scl[cin];
        int split = cin >> 4;
        int k = (cin & 15) * 8 + g;
        int s = k >> 5, q = (k >> 3) & 3, e = k & 7;
        int grp = (split * 9 + tap) * 4 + s;
        lds[grp * 32 + q * 8 + e] = (short)f2bf(w);
    }
    __syncthreads();
    const int* li = (const int*)lds;
    int* W3i = (int*)W3;
    for (int v = t; v < 2304; v += 256) {           // 144 groups x 16 ints
        int grp = v >> 4;
        W3i[grp * 1024 + oc * 16 + (v & 15)] = li[v];
    }
}

// out = sum of 4 partials (float4-vectorized, fully coalesced)
__global__ __launch_bounds__(256) void reduce_kernel(const floatx4* __restrict__ p,
                                                     floatx4* __restrict__ out) {
    int idx = blockIdx.x * blockDim.x + threadIdx.x;
    const int n4 = BB * COUT * HH * WW / 4;          // 262,144
    if (idx >= n4) return;
    const int stride = n4;
    out[idx] = p[idx] + p[idx + stride] + p[idx + 2 * stride] + p[idx + 3 * stride];
}

// Fused bases + implicit-GEMM conv, no atomics.
// Grid: 512 = 128 m-blocks x 4 splits (split = bid&3). Block: 4 waves.
// m-block: batch b, output rows h0..h0+3. Wave w: row h0+w (32 px = 32m) x all 64 oc.
// All 4 waves read identical B fragments each step -> L1 catches redundancy.
__global__ __launch_bounds__(256, 2) void conv_kernel(const float* __restrict__ xin,
                                                      const short* __restrict__ W3,
                                                      float* __restrict__ partial) {
    __shared__ short A[6 * 34 * 128];   // 52,224 B: [r(6)][x(34)][slot(16)][e(8)], slot=cl^(x&15)

    const int split = blockIdx.x & 3;
    const int mb = blockIdx.x >> 2;
    const int b = mb >> 3;
    const int h0 = (mb & 7) * 4;
    const int t = threadIdx.x;
    const int wave = t >> 6;
    const int lane = t & 63;
    const int l15 = lane & 15;
    const int q = lane >> 4;
    const int cin0 = split * CPS;

    // ---- prefetch first B fragments (no LDS dependency) ----
    const short* Wb = W3 + (size_t)split * 36 * 2048;
    short8 bq[4], bqn[4];
#pragma unroll
    for (int nt = 0; nt < 4; ++nt)
        bqn[nt] = *(const short8*)(Wb + (nt * 16 + l15) * 32 + q * 8);

    // ---- stage A: closed-form uniform cubic B-spline bases -> bf16 LDS ----
    for (int u = t; u < 6 * 34 * CPS; u += 256) {     // 3264 items, x-innermost
        int x34 = u % 34;
        int rc = u / 34;
        int cl = rc & 15;
        int r = rc >> 4;
        int y = h0 + r;
        float v = 0.0f;
        if (y >= 1 && y <= HH && x34 >= 1 && x34 <= WW)
            v = xin[((b * CINC + cin0 + cl) * HH + (y - 1)) * WW + (x34 - 1)];
        float sv = fmaf(v, 2.5f, 5.5f);               // (v + 2.2) / 0.4
        float cf = floorf(sv);
        int c = (int)cf;
        float f = sv - cf;
        float f2 = f * f, f3 = f2 * f;
        float omf = 1.0f - f;
        float w0 = f3 * (1.0f / 6.0f);
        float w1 = (1.0f + 3.0f * f + 3.0f * f2 - 3.0f * f3) * (1.0f / 6.0f);
        float w2 = (4.0f - 6.0f * f2 + 3.0f * f3) * (1.0f / 6.0f);
        float w3 = (omf * omf * omf) * (1.0f / 6.0f);
        short o8[8];
#pragma unroll
        for (int j = 0; j < 8; ++j) {
            float bj = (j == c) ? w0 : (j == c - 1) ? w1 : (j == c - 2) ? w2
                       : (j == c - 3) ? w3 : 0.0f;
            o8[j] = (short)f2bf(bj);
        }
        *(int4*)&A[(r * 34 + x34) * 128 + ((cl ^ (x34 & 15)) * 8)] = *(const int4*)o8;
    }
    __syncthreads();

    floatx4 acc[2][4];
#pragma unroll
    for (int mf = 0; mf < 2; ++mf)
#pragma unroll
        for (int nt = 0; nt < 4; ++nt) acc[mf][nt] = (floatx4)0.f;

    // ---- main loop: 36 steps = 9 taps x 4 k-quarters, 1-step B prefetch ----
#pragma unroll
    for (int ts = 0; ts < 36; ++ts) {
        const int tap = ts >> 2, s = ts & 3;
        const int kh = tap / 3, kw = tap % 3;
#pragma unroll
        for (int nt = 0; nt < 4; ++nt) bq[nt] = bqn[nt];
        if (ts < 35) {
            const short* wp = Wb + (size_t)(ts + 1) * 2048;
#pragma unroll
            for (int nt = 0; nt < 4; ++nt)
                bqn[nt] = *(const short8*)(wp + (nt * 16 + l15) * 32 + q * 8);
        }
#pragma unroll
        for (int mf = 0; mf < 2; ++mf) {
            const int xi = mf * 16 + l15 + kw;
            short8 aF = *(const short8*)&A[((wave + kh) * 34 + xi) * 128 +
                                           (((s * 4 + q) ^ (xi & 15)) * 8)];
#pragma unroll
            for (int nt = 0; nt < 4; ++nt)
                acc[mf][nt] = __builtin_amdgcn_mfma_f32_16x16x32_bf16(aF, bq[nt], acc[mf][nt], 0, 0, 0);
        }
    }

    // ---- epilogue: plain float4 stores to this split's partial buffer ----
    const int h = h0 + wave;
#pragma unroll
    for (int mf = 0; mf < 2; ++mf) {
#pragma unroll
        for (int nt = 0; nt < 4; ++nt) {
            const int oc = nt * 16 + l15;
            float* op = partial + ((((size_t)split * BB + b) * COUT + oc) * HH + h) * WW
                        + mf * 16 + q * 4;
            *(floatx4*)op = acc[mf][nt];
        }
    }
}

extern "C" void kernel_launch(void* const* d_in, const int* in_sizes, int n_in,
                              void* d_out, int out_size, void* d_ws, size_t ws_size,
                              hipStream_t stream) {
    const float* x  = (const float*)d_in[0];
    const float* sw = (const float*)d_in[1];
    const float* sc = (const float*)d_in[2];
    float* out = (float*)d_out;
    short* W3 = (short*)d_ws;                            // 294,912 bf16 = 576 KB
    float* partial = (float*)((char*)d_ws + 294912 * 2); // 4 x 4 MB fp32 partials

    wt_kernel<<<COUT, 256, 0, stream>>>(sw, sc, W3);
    conv_kernel<<<512, 256, 0, stream>>>(x, W3, partial);
    reduce_kernel<<<(out_size / 4 + 255) / 256, 256, 0, stream>>>(
        (const floatx4*)partial, (floatx4*)out);
}

// Round 7
// 95.832 us; speedup vs baseline: 1.0616x; 1.0616x over previous
//
#include <hip/hip_runtime.h>

#define CINC 64
#define COUT 64
#define HH 32
#define WW 32
#define BB 16
#define NSPLIT 4
#define CPS 16            // cin per split

typedef __attribute__((ext_vector_type(8))) short short8;
typedef __attribute__((ext_vector_type(4))) float floatx4;

__device__ __forceinline__ unsigned short f2bf(float f) {
    union { float f; unsigned int u; } c; c.f = f;
    unsigned int r = (c.u + 0x7FFFu + ((c.u >> 16) & 1u)) >> 16;
    return (unsigned short)r;
}

// W3 layout: [split(4)][tap(9)][s(4)][oc(64)][q(4)][e(8)] bf16
// k = s*32 + q*8 + e (0..127), cin = split*16 + k/8, g = k%8
// One block per oc: coalesced read of sw's contiguous 4608-float row, LDS
// transpose, coalesced 64B-group writes.
__global__ __launch_bounds__(256) void wt_kernel(const float* __restrict__ sw,
                                                 const float* __restrict__ sc,
                                                 short* __restrict__ W3) {
    __shared__ short lds[144 * 32];   // 9216 B
    __shared__ float scl[CINC];
    const int oc = blockIdx.x;
    const int t = threadIdx.x;
    if (t < CINC) scl[t] = sc[oc * CINC + t];
    __syncthreads();
    for (int j = t; j < 4608; j += 256) {           // sw row: [cin][g][kh*3+kw]
        float w = sw[oc * 4608 + j];
        int cin = j / 72;
        int rem = j - cin * 72;
        int g = rem / 9;
        int tap = rem - g * 9;
        w *= scl[cin];
        int split = cin >> 4;
        int k = (cin & 15) * 8 + g;
        int s = k >> 5, q = (k >> 3) & 3, e = k & 7;
        int grp = (split * 9 + tap) * 4 + s;
        lds[grp * 32 + q * 8 + e] = (short)f2bf(w);
    }
    __syncthreads();
    const int* li = (const int*)lds;
    int* W3i = (int*)W3;
    for (int v = t; v < 2304; v += 256) {           // 144 groups x 16 ints
        int grp = v >> 4;
        W3i[grp * 1024 + oc * 16 + (v & 15)] = li[v];
    }
}

// out = sum of 4 partials (float4-vectorized, fully coalesced)
__global__ __launch_bounds__(256) void reduce_kernel(const floatx4* __restrict__ p,
                                                     floatx4* __restrict__ out) {
    int idx = blockIdx.x * blockDim.x + threadIdx.x;
    const int n4 = BB * COUT * HH * WW / 4;          // 262,144
    if (idx >= n4) return;
    const int stride = n4;
    out[idx] = p[idx] + p[idx + stride] + p[idx + 2 * stride] + p[idx + 3 * stride];
}

// Fused bases + implicit-GEMM conv, no atomics.  (R4 configuration — best measured.)
// Grid: 512 = 128 m-blocks x 4 splits (split = bid&3). Block: 4 waves = 2m x 2n.
// m-block: batch b, output rows h0..h0+3 (128 px). Wave: rows h0+2*wm..+1 (64m), oc half n0 (32n).
__global__ __launch_bounds__(256, 2) void conv_kernel(const float* __restrict__ xin,
                                                      const short* __restrict__ W3,
                                                      float* __restrict__ partial) {
    __shared__ short A[6 * 34 * 128];   // 52,224 B: [r(6)][x(34)][slot(16)][e(8)], slot=cl^(x&15)

    const int split = blockIdx.x & 3;
    const int mb = blockIdx.x >> 2;
    const int b = mb >> 3;
    const int h0 = (mb & 7) * 4;
    const int t = threadIdx.x;
    const int wave = t >> 6;
    const int lane = t & 63;
    const int l15 = lane & 15;
    const int q = lane >> 4;
    const int wm = wave >> 1;            // m-half: rows h0+2*wm, h0+2*wm+1
    const int n0 = (wave & 1) * 32;
    const int cin0 = split * CPS;

    // ---- prefetch first B fragments (no LDS dependency) ----
    const short* Wb = W3 + (size_t)split * 36 * 2048;
    short8 bq[2], bqn[2];
#pragma unroll
    for (int nt = 0; nt < 2; ++nt)
        bqn[nt] = *(const short8*)(Wb + (n0 + nt * 16 + l15) * 32 + q * 8);

    // ---- stage A: closed-form uniform cubic B-spline bases -> bf16 LDS ----
    for (int u = t; u < 6 * 34 * CPS; u += 256) {     // 3264 items, x-innermost
        int x34 = u % 34;
        int rc = u / 34;
        int cl = rc & 15;
        int r = rc >> 4;
        int y = h0 + r;
        float v = 0.0f;
        if (y >= 1 && y <= HH && x34 >= 1 && x34 <= WW)
            v = xin[((b * CINC + cin0 + cl) * HH + (y - 1)) * WW + (x34 - 1)];
        float sv = fmaf(v, 2.5f, 5.5f);               // (v + 2.2) / 0.4
        float cf = floorf(sv);
        int c = (int)cf;
        float f = sv - cf;
        float f2 = f * f, f3 = f2 * f;
        float omf = 1.0f - f;
        float w0 = f3 * (1.0f / 6.0f);
        float w1 = (1.0f + 3.0f * f + 3.0f * f2 - 3.0f * f3) * (1.0f / 6.0f);
        float w2 = (4.0f - 6.0f * f2 + 3.0f * f3) * (1.0f / 6.0f);
        float w3 = (omf * omf * omf) * (1.0f / 6.0f);
        short o8[8];
#pragma unroll
        for (int j = 0; j < 8; ++j) {
            float bj = (j == c) ? w0 : (j == c - 1) ? w1 : (j == c - 2) ? w2
                       : (j == c - 3) ? w3 : 0.0f;
            o8[j] = (short)f2bf(bj);
        }
        *(int4*)&A[(r * 34 + x34) * 128 + ((cl ^ (x34 & 15)) * 8)] = *(const int4*)o8;
    }
    __syncthreads();

    floatx4 acc[4][2];
#pragma unroll
    for (int mf = 0; mf < 4; ++mf)
#pragma unroll
        for (int nt = 0; nt < 2; ++nt) acc[mf][nt] = (floatx4)0.f;

    // ---- main loop: 36 steps = 9 taps x 4 k-quarters, 1-step B prefetch ----
#pragma unroll
    for (int ts = 0; ts < 36; ++ts) {
        const int tap = ts >> 2, s = ts & 3;
        const int kh = tap / 3, kw = tap % 3;
#pragma unroll
        for (int nt = 0; nt < 2; ++nt) bq[nt] = bqn[nt];
        if (ts < 35) {
            const short* wp = Wb + (size_t)(ts + 1) * 2048;
#pragma unroll
            for (int nt = 0; nt < 2; ++nt)
                bqn[nt] = *(const short8*)(wp + (n0 + nt * 16 + l15) * 32 + q * 8);
        }
#pragma unroll
        for (int mf = 0; mf < 4; ++mf) {
            const int rloc = 2 * wm + (mf >> 1);
            const int xi = (mf & 1) * 16 + l15 + kw;
            short8 aF = *(const short8*)&A[((rloc + kh) * 34 + xi) * 128 +
                                           (((s * 4 + q) ^ (xi & 15)) * 8)];
#pragma unroll
            for (int nt = 0; nt < 2; ++nt)
                acc[mf][nt] = __builtin_amdgcn_mfma_f32_16x16x32_bf16(aF, bq[nt], acc[mf][nt], 0, 0, 0);
        }
    }

    // ---- epilogue: plain float4 stores to this split's partial buffer ----
#pragma unroll
    for (int mf = 0; mf < 4; ++mf) {
        const int h = h0 + 2 * wm + (mf >> 1);
        const int wcol = (mf & 1) * 16 + q * 4;
#pragma unroll
        for (int nt = 0; nt < 2; ++nt) {
            const int oc = n0 + nt * 16 + l15;
            float* op = partial + ((((size_t)split * BB + b) * COUT + oc) * HH + h) * WW + wcol;
            *(floatx4*)op = acc[mf][nt];
        }
    }
}

extern "C" void kernel_launch(void* const* d_in, const int* in_sizes, int n_in,
                              void* d_out, int out_size, void* d_ws, size_t ws_size,
                              hipStream_t stream) {
    const float* x  = (const float*)d_in[0];
    const float* sw = (const float*)d_in[1];
    const float* sc = (const float*)d_in[2];
    float* out = (float*)d_out;
    short* W3 = (short*)d_ws;                            // 294,912 bf16 = 576 KB
    float* partial = (float*)((char*)d_ws + 294912 * 2); // 4 x 4 MB fp32 partials

    wt_kernel<<<COUT, 256, 0, stream>>>(sw, sc, W3);
    conv_kernel<<<512, 256, 0, stream>>>(x, W3, partial);
    reduce_kernel<<<(out_size / 4 + 255) / 256, 256, 0, stream>>>(
        (const floatx4*)partial, (floatx4*)out);
}